// Round 5
// baseline (187.976 us; speedup 1.0000x reference)
//
#include <hip/hip_runtime.h>
#include <stdint.h>
#include <math.h>

#define NSEG 65536
#define D 64

typedef float f32x4 __attribute__((ext_vector_type(4)));

// Phase 1: scan-based boundary detection over the SORTED index.
// Each thread handles 16 consecutive ints (4 x int4, coalesced). For each
// change-point index[i-1]=prev -> index[i]=cur, start[s]=i for s in (prev,cur].
// Thread covering the last element also fills start[s]=N for s>index[N-1].
__global__ __launch_bounds__(256) void seg_bounds_scan(const int* __restrict__ index,
                                                       int N, int* __restrict__ start) {
    const int t  = blockIdx.x * 256 + threadIdx.x;
    const int i0 = t * 16;
    if (i0 >= N) return;

    int prev = (i0 == 0) ? -1 : index[i0 - 1];

    int4 a0 = reinterpret_cast<const int4*>(index + i0)[0];
    int4 a1 = reinterpret_cast<const int4*>(index + i0)[1];
    int4 a2 = reinterpret_cast<const int4*>(index + i0)[2];
    int4 a3 = reinterpret_cast<const int4*>(index + i0)[3];
    int v[16] = {a0.x, a0.y, a0.z, a0.w, a1.x, a1.y, a1.z, a1.w,
                 a2.x, a2.y, a2.z, a2.w, a3.x, a3.y, a3.z, a3.w};

#pragma unroll
    for (int j = 0; j < 16; ++j) {
        const int cur = v[j];
        if (cur != prev) {
            for (int s = prev + 1; s <= cur; ++s) start[s] = i0 + j;
            prev = cur;
        }
    }
    if (i0 + 16 >= N) {  // last thread: tail segments are empty, start = N
        for (int s = prev + 1; s <= NSEG; ++s) start[s] = N;
    }
}

#define FMAX4(acc, v) do { \
    (acc).x = fmaxf((acc).x, (v).x); (acc).y = fmaxf((acc).y, (v).y); \
    (acc).z = fmaxf((acc).z, (v).z); (acc).w = fmaxf((acc).w, (v).w); } while (0)

#define NTLOAD(r) __builtin_nontemporal_load( \
    reinterpret_cast<const f32x4*>(x + (size_t)(r) * D + col4))

// Phase 2: one wave per segment. 16 lanes/row, float4/lane, nontemporal
// streaming loads. Main loop: 16 rows/iter into 4 independent accumulators
// (4 loads in flight/lane before any dependent fmax). Tail cascade 8->4->
// predicated 0-3 rows. Cross-sub reduce via shfl_xor(16|32); lanes 0..15
// store one coalesced 256B row per segment.
__global__ __launch_bounds__(256) void segmax_kernel(const float* __restrict__ x,
                                                     const int* __restrict__ start,
                                                     float* __restrict__ out) {
    const int lane = threadIdx.x & 63;
    const int wave = threadIdx.x >> 6;
    const int s = blockIdx.x * 4 + wave;

    const int rs = start[s];
    const int re = start[s + 1];

    const int sub  = lane >> 4;        // row within each 4-row group
    const int col4 = (lane & 15) * 4;  // this lane's float4 column

    f32x4 m;
    if (rs < re) {
        f32x4 m0 = {-INFINITY, -INFINITY, -INFINITY, -INFINITY};
        f32x4 m1 = m0, m2 = m0, m3 = m0;
        int r0 = rs;
        for (; r0 + 16 <= re; r0 += 16) {
            const f32x4 v0 = NTLOAD(r0 + sub);
            const f32x4 v1 = NTLOAD(r0 + 4 + sub);
            const f32x4 v2 = NTLOAD(r0 + 8 + sub);
            const f32x4 v3 = NTLOAD(r0 + 12 + sub);
            FMAX4(m0, v0); FMAX4(m1, v1); FMAX4(m2, v2); FMAX4(m3, v3);
        }
        if (r0 + 8 <= re) {
            const f32x4 v0 = NTLOAD(r0 + sub);
            const f32x4 v1 = NTLOAD(r0 + 4 + sub);
            FMAX4(m0, v0); FMAX4(m1, v1);
            r0 += 8;
        }
        if (r0 + 4 <= re) {
            const f32x4 v = NTLOAD(r0 + sub);
            FMAX4(m2, v);
            r0 += 4;
        }
        const int r = r0 + sub;
        if (r < re) {  // 0-3 leftover rows, exec-masked
            const f32x4 v = NTLOAD(r);
            FMAX4(m3, v);
        }
        FMAX4(m0, m1); FMAX4(m2, m3); FMAX4(m0, m2);
        m = m0;
        // reduce across the 4 sub-rows (lane bits 4..5)
        m.x = fmaxf(m.x, __shfl_xor(m.x, 16));
        m.y = fmaxf(m.y, __shfl_xor(m.y, 16));
        m.z = fmaxf(m.z, __shfl_xor(m.z, 16));
        m.w = fmaxf(m.w, __shfl_xor(m.w, 16));
        m.x = fmaxf(m.x, __shfl_xor(m.x, 32));
        m.y = fmaxf(m.y, __shfl_xor(m.y, 32));
        m.z = fmaxf(m.z, __shfl_xor(m.z, 32));
        m.w = fmaxf(m.w, __shfl_xor(m.w, 32));
    } else {
        m = (f32x4){0.0f, 0.0f, 0.0f, 0.0f};  // empty segment -> 0
    }

    if (lane < 16) {
        *reinterpret_cast<f32x4*>(out + (size_t)s * D + col4) = m;
    }
}

extern "C" void kernel_launch(void* const* d_in, const int* in_sizes, int n_in,
                              void* d_out, int out_size, void* d_ws, size_t ws_size,
                              hipStream_t stream) {
    const float* x   = (const float*)d_in[0];
    const int* index = (const int*)d_in[1];
    float* out       = (float*)d_out;
    int* start       = (int*)d_ws;  // NSEG+1 ints of scratch

    const int N = in_sizes[0] / D;  // 4194304 rows

    seg_bounds_scan<<<(N / 16 + 255) / 256, 256, 0, stream>>>(index, N, start);
    segmax_kernel<<<NSEG / 4, 256, 0, stream>>>(x, start, out);
}